// Round 14
// baseline (759.765 us; speedup 1.0000x reference)
//
#include <hip/hip_runtime.h>
#include <hip/hip_bf16.h>

// ShardAttention R17: R16 (best, 730.9us) + scores store-path fix.
// Scores was store-line-efficiency-bound: direct stores 4B/lane (50% line),
// mirror stores 8B at 4KB stride (~25-50%) -> RMW inflation. Now shuffle-
// assemble 16B uint4 segments in-register: direct via shfl_xor(2,4) chain
// (lanes lr%8==0 store 8 contiguous cols); mirror via shfl_xor(16) lq-pair
// merge (even-lq lanes store 8 contiguous rows). Same bytes, ~100% line
// coverage, 4x fewer store instructions. GEMM/proj/reduce = exact R16.

typedef __hip_bfloat16 bf16;
typedef __bf16 bf16x8 __attribute__((ext_vector_type(8)));
typedef float f32x4 __attribute__((ext_vector_type(4)));

#define B_ 2
#define T_ 2048
#define C_ 1024
#define H_ 16
#define D_ 16384
#define E_ 1024
#define KZ_ 4  // proj split-K chunks

__device__ __forceinline__ void load_lds16(const void* g, void* l) {
  __builtin_amdgcn_global_load_lds(
      (const __attribute__((address_space(1))) void*)g,
      (__attribute__((address_space(3))) void*)l, 16, 0, 0);
}

__device__ __forceinline__ unsigned pack2(float a, float b) {
  union { bf16 h[2]; unsigned u; } p;
  p.h[0] = __float2bfloat16(a);
  p.h[1] = __float2bfloat16(b);
  return p.u;
}

// ---------------- transpose + fp32->bf16 cast ----------------
__global__ __launch_bounds__(256) void transpose_cast_kernel(
    const float* __restrict__ in, bf16* __restrict__ out, int rows, int cols) {
  __shared__ float tile[32][33];
  size_t zoff = (size_t)blockIdx.z * rows * cols;
  int c0 = blockIdx.x * 32, r0 = blockIdx.y * 32;
  int tx = threadIdx.x, ty = threadIdx.y;
  for (int i = ty; i < 32; i += 8)
    tile[i][tx] = in[zoff + (size_t)(r0 + i) * cols + c0 + tx];
  __syncthreads();
  for (int i = ty; i < 32; i += 8)
    out[zoff + (size_t)(c0 + i) * rows + r0 + tx] = __float2bfloat16(tile[tx][i]);
}

// ---------------- x -> per-head bf16 [b][h][t][64] ----------------
__global__ __launch_bounds__(256) void xh_cast_kernel(
    const float* __restrict__ x, bf16* __restrict__ xh) {
  int bt = blockIdx.x;
  int b = bt >> 11, t = bt & (T_ - 1);
  float4 v = ((const float4*)(x + (size_t)bt * C_))[threadIdx.x];
  int c = threadIdx.x * 4;
  int h = c >> 6, k = c & 63;
  bf16* o = xh + ((size_t)(b * H_ + h) * T_ + t) * 64 + k;
  o[0] = __float2bfloat16(v.x);
  o[1] = __float2bfloat16(v.y);
  o[2] = __float2bfloat16(v.z);
  o[3] = __float2bfloat16(v.w);
}

// ---------------- reduce KZ_ bf16 partials -> f32 out ----------------
__global__ __launch_bounds__(256) void reduce_kernel(
    const bf16* __restrict__ p, float* __restrict__ out, int n8) {
  int i = blockIdx.x * 256 + threadIdx.x;
  if (i >= n8) return;
  float a[8] = {};
#pragma unroll
  for (int z = 0; z < KZ_; ++z) {
    bf16x8 v = ((const bf16x8*)(p + (size_t)z * n8 * 8))[i];
#pragma unroll
    for (int k = 0; k < 8; ++k) a[k] += (float)v[k];
  }
  float4 lo = make_float4(a[0], a[1], a[2], a[3]);
  float4 hi = make_float4(a[4], a[5], a[6], a[7]);
  ((float4*)out)[2 * i] = lo;
  ((float4*)out)[2 * i + 1] = hi;
}

// ---------------- scores: symmetric tiles, K=64, exp + sums ----------------
__global__ __launch_bounds__(256) void scores_kernel(
    const bf16* __restrict__ xh,  // [Hs][T][64]
    bf16* __restrict__ P,         // [Hs][T][T]
    float* __restrict__ lsum) {   // [Hs][T], pre-zeroed
  int L = blockIdx.x;
  int z = blockIdx.y;
  int ti = 0, rem = L;
  while (rem >= H_ - ti) { rem -= H_ - ti; ++ti; }
  int tj = ti + rem;  // ti <= tj

  const bf16* A = xh + (size_t)z * T_ * 64;
  bf16* Pz = P + (size_t)z * T_ * T_;
  size_t row0 = (size_t)ti * 128, col0 = (size_t)tj * 128;

  __shared__ bf16 lds_a[128 * 64];
  __shared__ bf16 lds_b[128 * 64];
  int t = threadIdx.x;

  const bf16* ga = A + (row0 + (t >> 3)) * 64 + (t & 7) * 8;
  const bf16* gb = A + (col0 + (t >> 3)) * 64 + (t & 7) * 8;
#pragma unroll
  for (int q = 0; q < 4; ++q) {
    load_lds16(ga + q * 32 * 64, lds_a + t * 8 + q * 2048);
    load_lds16(gb + q * 32 * 64, lds_b + t * 8 + q * 2048);
  }
  __syncthreads();

  int lane = t & 63, w = t >> 6;
  int wm = (w & 1) * 64, wn = (w >> 1) * 64;
  int lr = lane & 15, lq = lane >> 4;
  const int a_off = (wm + lr) * 64 + lq * 8;
  const int b_off = (wn + lr) * 64 + lq * 8;

  f32x4 acc[4][4] = {};
#pragma unroll
  for (int kh = 0; kh < 2; ++kh) {
    bf16x8 af[4], bfr[4];
#pragma unroll
    for (int i = 0; i < 4; ++i)
      af[i] = *(const bf16x8*)&lds_a[a_off + kh * 32 + i * 16 * 64];
#pragma unroll
    for (int j = 0; j < 4; ++j)
      bfr[j] = *(const bf16x8*)&lds_b[b_off + kh * 32 + j * 16 * 64];
#pragma unroll
    for (int i = 0; i < 4; ++i)
#pragma unroll
      for (int j = 0; j < 4; ++j)
        acc[i][j] = __builtin_amdgcn_mfma_f32_16x16x32_bf16(af[i], bfr[j],
                                                            acc[i][j], 0, 0, 0);
  }

  float rs[4][4];
  float cs[4];
#pragma unroll
  for (int i2 = 0; i2 < 4; ++i2)
#pragma unroll
    for (int reg = 0; reg < 4; ++reg) rs[i2][reg] = 0.f;
#pragma unroll
  for (int j2 = 0; j2 < 4; ++j2) cs[j2] = 0.f;

#pragma unroll
  for (int i2 = 0; i2 < 4; ++i2) {
    size_t rb = row0 + wm + i2 * 16 + lq * 4;
#pragma unroll
    for (int j2 = 0; j2 < 4; ++j2) {
      size_t c = col0 + wn + j2 * 16 + lr;
      float e[4];
      unsigned p[4];
#pragma unroll
      for (int reg = 0; reg < 4; ++reg) {
        e[reg] = __expf(acc[i2][j2][reg] * 0.125f);
        rs[i2][reg] += e[reg];
        cs[j2] += e[reg];
        // cols (lr, lr^1) of row rb+reg; valid on even lr
        p[reg] = pack2(e[reg], __shfl_xor(e[reg], 1));
      }
      // direct: assemble 16B (8 cols) per row; lanes lr%8==0 store uint4.
      // chain validity: even lanes hold valid p; xor(2) partner is even;
      // lanes lr%4==0 hold valid (a0,a1); xor(4) partner is %4==0.
#pragma unroll
      for (int reg = 0; reg < 4; ++reg) {
        unsigned a0 = p[reg];
        unsigned a1 = __shfl_xor((int)p[reg], 2);   // cols lr+2,lr+3
        unsigned b0 = __shfl_xor((int)a0, 4);       // cols lr+4,lr+5
        unsigned b1 = __shfl_xor((int)a1, 4);       // cols lr+6,lr+7
        if ((lr & 7) == 0) {
          uint4 v = make_uint4(a0, a1, b0, b1);
          *(uint4*)&Pz[(rb + reg) * T_ + c] = v;    // c is 8-aligned here
        }
      }
      // mirror: rows rb..rb+3 (uint2) + lq-partner rows -> 16B (8 rows);
      // even-lq lanes store uint4 at P[c][..].
      uint2 mv;
      mv.x = pack2(e[0], e[1]);
      mv.y = pack2(e[2], e[3]);
      unsigned m0 = __shfl_xor((int)mv.x, 16);      // partner lq^1 rows
      unsigned m1 = __shfl_xor((int)mv.y, 16);
      if ((lq & 1) == 0) {
        uint4 v = make_uint4(mv.x, mv.y, m0, m1);   // rows lq*4 .. lq*4+7
        *(uint4*)&Pz[c * T_ + rb] = v;              // rb is 8-aligned here
      }
    }
  }

#pragma unroll
  for (int i2 = 0; i2 < 4; ++i2)
#pragma unroll
    for (int reg = 0; reg < 4; ++reg) {
#pragma unroll
      for (int off = 1; off < 16; off <<= 1)
        rs[i2][reg] += __shfl_xor(rs[i2][reg], off);
    }
  if (lr == 0) {
#pragma unroll
    for (int i2 = 0; i2 < 4; ++i2) {
      size_t rb = row0 + wm + i2 * 16 + lq * 4;
#pragma unroll
      for (int reg = 0; reg < 4; ++reg)
        atomicAdd(&lsum[(size_t)z * T_ + rb + reg], rs[i2][reg]);
    }
  }
  if (ti != tj) {
#pragma unroll
    for (int j2 = 0; j2 < 4; ++j2) {
      cs[j2] += __shfl_xor(cs[j2], 16);
      cs[j2] += __shfl_xor(cs[j2], 32);
    }
    if (lq == 0) {
#pragma unroll
      for (int j2 = 0; j2 < 4; ++j2) {
        size_t c = col0 + wn + j2 * 16 + lr;
        atomicAdd(&lsum[(size_t)z * T_ + c], cs[j2]);
      }
    }
  }
}

// ---------------- 256^2 bf16 NT GEMM (R8: 5-bar slipped, vmcnt(6)) ----------
template <int IH, int JH>
__device__ __forceinline__ void quad(f32x4 (&acc)[8][4], const bf16x8 (&aR)[8],
                                     const bf16x8 (&bR)[4]) {
#pragma unroll
  for (int i = 0; i < 4; ++i)
#pragma unroll
    for (int jj = 0; jj < 2; ++jj)
#pragma unroll
      for (int kk = 0; kk < 2; ++kk)
        acc[IH * 4 + i][JH * 2 + jj] = __builtin_amdgcn_mfma_f32_16x16x32_bf16(
            aR[i * 2 + kk], bR[jj * 2 + kk], acc[IH * 4 + i][JH * 2 + jj], 0, 0,
            0);
}

#define STAGE_A(bufi, h, tau)                                                 \
  do {                                                                        \
    load_lds16(Ab + offA[(h)*2 + 0] + (size_t)(tau)*64,                       \
               &ldsA[bufi][(((h)*512) + t) * 8]);                             \
    load_lds16(Ab + offA[(h)*2 + 1] + (size_t)(tau)*64,                       \
               &ldsA[bufi][((1024 + (h)*512) + t) * 8]);                      \
  } while (0)

#define STAGE_B(bufi, h, tau)                                                 \
  do {                                                                        \
    load_lds16(Bb + offB[(h)*2 + 0] + (size_t)(tau)*64,                       \
               &ldsB[bufi][(((t >> 8) * 512) + (h)*256 + (t & 255)) * 8]);    \
    load_lds16(                                                               \
        Bb + offB[(h)*2 + 1] + (size_t)(tau)*64,                              \
        &ldsB[bufi][((((t + 512) >> 8) * 512) + (h)*256 + (t & 255)) * 8]);   \
  } while (0)

#define RD_A(dst, d, add)                                                     \
  do {                                                                        \
    dst[0] = *(const bf16x8*)&ldsA[d][aoff[0] + (add)];                       \
    dst[1] = *(const bf16x8*)&ldsA[d][aoff[1] + (add)];                       \
    dst[2] = *(const bf16x8*)&ldsA[d][aoff[2] + (add)];                       \
    dst[3] = *(const bf16x8*)&ldsA[d][aoff[3] + (add)];                       \
    dst[4] = *(const bf16x8*)&ldsA[d][aoff[4] + (add)];                       \
    dst[5] = *(const bf16x8*)&ldsA[d][aoff[5] + (add)];                       \
    dst[6] = *(const bf16x8*)&ldsA[d][aoff[6] + (add)];                       \
    dst[7] = *(const bf16x8*)&ldsA[d][aoff[7] + (add)];                       \
  } while (0)

#define RD_B(dst, d, add)                                                     \
  do {                                                                        \
    dst[0] = *(const bf16x8*)&ldsB[d][boff[0] + (add)];                       \
    dst[1] = *(const bf16x8*)&ldsB[d][boff[1] + (add)];                       \
    dst[2] = *(const bf16x8*)&ldsB[d][boff[2] + (add)];                       \
    dst[3] = *(const bf16x8*)&ldsB[d][boff[3] + (add)];                       \
  } while (0)

// MODE 1: pack-store bf16   MODE 3: pack-store bf16(v / lsum[bz*lzs + r])
template <int MODE, int SWZ>
__global__ __launch_bounds__(512, 2) void gemm256_kernel(
    const bf16* __restrict__ A, long long a_zstride, int lda,
    const bf16* __restrict__ BT, long long b_zstride, int ldb,
    void* __restrict__ Cout, int ldc, long long c_zflat,
    const float* __restrict__ lsum, int lzs, int K) {
  __shared__ __align__(16) bf16 ldsA[2][256 * 64];
  __shared__ __align__(16) bf16 ldsB[2][256 * 64];
  const int t = threadIdx.x;

  int bx = blockIdx.x, by = blockIdx.y, bz = blockIdx.z;
  if (SWZ) {
    int gx = gridDim.x, gy = gridDim.y, gz = gridDim.z;
    int S = gy * gz, nb = gx * S;
    if (((S & 7) == 0) && ((nb & 7) == 0)) {
      int L = bx + gx * (by + gy * bz);
      int xcd = L & 7, m = L >> 3, spx = S >> 3;
      int col = m % gx, sl = m / gx;
      int strip = xcd * spx + sl;
      bx = col; by = strip % gy; bz = strip / gy;
    }
  }

  const bf16* Ab = A + (size_t)bz * a_zstride;
  const bf16* Bb = BT + (size_t)bz * b_zstride;
  const size_t row0 = (size_t)by * 256;
  const size_t col0 = (size_t)bx * 256;
  const int NT = K >> 6;

  // staging source element-offsets (swizzle involution pre-applied to SOURCE)
  int offA[4], offB[4];
#pragma unroll
  for (int h = 0; h < 2; ++h)
#pragma unroll
    for (int l = 0; l < 2; ++l) {
      int s = h * 512 + l * 1024 + t;
      int src = s ^ ((s >> 3) & 7);
      offA[h * 2 + l] =
          (int)((row0 + (size_t)(src >> 3)) * (size_t)lda) + (src & 7) * 8;
      int u = t + l * 512;
      int sb = (u >> 8) * 512 + h * 256 + (u & 255);
      int srcb = sb ^ ((sb >> 3) & 7);
      offB[h * 2 + l] =
          (int)((col0 + (size_t)(srcb >> 3)) * (size_t)ldb) + (srcb & 7) * 8;
    }

  // fragment read offsets (elements), swizzled: phys = logical ^ ((row&7)<<3)
  const int lane = t & 63, w = t >> 6;
  const int wr = w >> 2, wc = w & 3;
  const int lr = lane & 15, lq = lane >> 4;
  const int axor = (lr & 7) << 3;
  int aoff[8], boff[4];
#pragma unroll
  for (int i = 0; i < 4; ++i)
#pragma unroll
    for (int kk = 0; kk < 2; ++kk)
      aoff[i * 2 + kk] =
          (((wr * 128 + i * 16 + lr) * 64) + kk * 32 + lq * 8) ^ axor;
#pragma unroll
  for (int j = 0; j < 2; ++j)
#pragma unroll
    for (int kk = 0; kk < 2; ++kk)
      boff[j * 2 + kk] =
          (((wc * 64 + j * 16 + lr) * 64) + kk * 32 + lq * 8) ^ axor;

  f32x4 acc[8][4] = {};
  bf16x8 aR[8], bR0[4], bR1[4];

  // prologue: stream A0(0),B0(0),B1(0),A1(0),A0(1),B0(1),B1(1); drain to 3 halves
  {
    const int t1 = (NT > 1) ? 1 : 0;
    STAGE_A(0, 0, 0);
    STAGE_B(0, 0, 0);
    STAGE_B(0, 1, 0);
    STAGE_A(0, 1, 0);
    STAGE_A(1, 0, t1);
    STAGE_B(1, 0, t1);
    STAGE_B(1, 1, t1);
    asm volatile("s_waitcnt vmcnt(6)" ::: "memory");
    __builtin_amdgcn_s_barrier();
  }

  for (int tt = 0; tt < NT; ++tt) {
    const int d = tt & 1, dn = d ^ 1;
    const int tp1 = (tt + 1 < NT) ? (tt + 1) : (NT - 1);
    const int tp2 = (tt + 2 < NT) ? (tt + 2) : (NT - 1);
    // ---- ph1: reads{jh0,ih0}; bar; q(0,0); stage A1(t+1)->dn
    RD_B(bR0, d, 0);
    RD_A(aR, d, 0);
    __builtin_amdgcn_s_barrier();
    __builtin_amdgcn_s_setprio(1);
    quad<0, 0>(acc, aR, bR0);
    __builtin_amdgcn_s_setprio(0);
    STAGE_A(dn, 1, tp1);
    // ---- ph2: reads{jh1}; bar; q(0,1); stage A0(t+2)->d
    RD_B(bR1, d, 2048);
    __builtin_amdgcn_s_barrier();
    __builtin_amdgcn_s_setprio(1);
    quad<0, 1>(acc, aR, bR1);
    __builtin_amdgcn_s_setprio(0);
    STAGE_A(d, 0, tp2);
    // ---- ph3: reads{ih1}; bar; q(1,1); stage B0(t+2)->d
    RD_A(aR, d, 4096);
    __builtin_amdgcn_s_barrier();
    __builtin_amdgcn_s_setprio(1);
    quad<1, 1>(acc, aR, bR1);
    __builtin_amdgcn_s_setprio(0);
    STAGE_B(d, 0, tp2);
    // ---- ph4: bar; q(1,0); stage B1(t+2)->d; counted vmcnt; tile-bar
    __builtin_amdgcn_s_barrier();
    __builtin_amdgcn_s_setprio(1);
    quad<1, 0>(acc, aR, bR0);
    __builtin_amdgcn_s_setprio(0);
    STAGE_B(d, 1, tp2);
    asm volatile("s_waitcnt vmcnt(6)" ::: "memory");
    __builtin_amdgcn_s_barrier();
  }
  // drain outstanding gloads before workgroup retire (LDS reuse safety)
  asm volatile("s_waitcnt vmcnt(0)" ::: "memory");

  // epilogue: C/D layout col=lane&15, row=(lane>>4)*4+reg; column-pair packing
  size_t cbase = (size_t)bz * c_zflat + col0 + wc * 64;
#pragma unroll
  for (int i = 0; i < 8; ++i) {
    size_t r = row0 + wr * 128 + i * 16 + lq * 4;
    float4 inv4 = make_float4(1.f, 1.f, 1.f, 1.f);
    if (MODE == 3) {
      float4 lv = *(const float4*)&lsum[(size_t)bz * lzs + r];
      inv4 = make_float4(1.f / lv.x, 1.f / lv.y, 1.f / lv.z, 1.f / lv.w);
    }
#pragma unroll
    for (int j = 0; j < 4; ++j) {
      size_t c = cbase + j * 16 + lr;
#pragma unroll
      for (int reg = 0; reg < 4; ++reg) {
        float v = acc[i][j][reg];
        if (MODE == 3) {
          float iv = reg == 0 ? inv4.x : reg == 1 ? inv4.y : reg == 2 ? inv4.z
                                                                      : inv4.w;
          v *= iv;
        }
        float nb = __shfl_xor(v, 1);
        if ((lr & 1) == 0) {
          size_t idx = (r + reg) * (size_t)ldc + c;
          *(unsigned*)&((bf16*)Cout)[idx] = pack2(v, nb);
        }
      }
    }
  }
}

extern "C" void kernel_launch(void* const* d_in, const int* in_sizes, int n_in,
                              void* d_out, int out_size, void* d_ws,
                              size_t ws_size, hipStream_t stream) {
  const float* x = (const float*)d_in[0];    // [B, T, C] fp32
  const float* wgt = (const float*)d_in[1];  // [D, E] fp32
  float* out = (float*)d_out;                // [B, T, E] fp32

  // ws layout
  bf16* xbT = (bf16*)d_ws;                        // [B][C][T]    8 MB
  bf16* wbT = xbT + (size_t)B_ * C_ * T_;         // [E][D]      32 MB
  bf16* xh = wbT + (size_t)E_ * D_;               // [B][H][T][64] 8 MB
  bf16* Obuf = xh + (size_t)B_ * H_ * T_ * 64;    // [B*T][D]   128 MB
  float* lsum = (float*)(Obuf + (size_t)B_ * T_ * D_);  // [16][T] 128 KB
  bf16* P = (bf16*)(lsum + (size_t)16 * T_);      // [Hs][T][T] slab 128 MB
  bf16* partials = P;                             // reuse slab (34 MB, KZ=4)

  transpose_cast_kernel<<<dim3(C_ / 32, T_ / 32, B_), dim3(32, 8), 0, stream>>>(
      x, xbT, T_, C_);
  transpose_cast_kernel<<<dim3(E_ / 32, D_ / 32, 1), dim3(32, 8), 0, stream>>>(
      wgt, wbT, D_, E_);
  xh_cast_kernel<<<B_ * T_, 256, 0, stream>>>(x, xh);

  size_t fixed_bytes = ((size_t)B_ * C_ * T_ + (size_t)E_ * D_ +
                        (size_t)B_ * H_ * T_ * 64 + (size_t)B_ * T_ * D_) * 2 +
                       (size_t)16 * T_ * 4;
  int Hs = 16;
  while (Hs > 1 && fixed_bytes + (size_t)Hs * T_ * T_ * 2 > ws_size) Hs >>= 1;

  for (int b = 0; b < B_; ++b) {
    for (int h0 = 0; h0 < H_; h0 += Hs) {
      const bf16* xhb = xh + (size_t)(b * H_ + h0) * T_ * 64;
      hipMemsetAsync(lsum, 0, (size_t)Hs * T_ * sizeof(float), stream);
      scores_kernel<<<dim3(136, Hs), 256, 0, stream>>>(xhb, P, lsum);
      // O = (P @ xbT^T) / l
      gemm256_kernel<3, 1><<<dim3(C_ / 256, T_ / 256, Hs), 512, 0, stream>>>(
          P, (long long)T_ * T_, T_, xbT + (size_t)b * C_ * T_, 0LL, T_,
          (void*)(Obuf + (size_t)b * T_ * D_ + (size_t)h0 * C_), D_,
          (long long)C_, lsum, T_, T_);
    }
  }
  // proj: partials[z] = O[:, z*4096:(z+1)*4096] @ W[z*4096:(z+1)*4096, :]
  gemm256_kernel<1, 1><<<dim3(E_ / 256, (B_ * T_) / 256, KZ_), 512, 0,
                         stream>>>(Obuf, (long long)(D_ / KZ_), D_, wbT,
                                   (long long)(D_ / KZ_), D_, (void*)partials,
                                   E_, (long long)B_ * T_ * E_, nullptr, 0,
                                   D_ / KZ_);
  reduce_kernel<<<(B_ * T_ * E_ / 8 + 255) / 256, 256, 0, stream>>>(
      partials, out, B_ * T_ * E_ / 8);
}

// Round 15
// 730.163 us; speedup vs baseline: 1.0405x; 1.0405x over previous
//
#include <hip/hip_runtime.h>
#include <hip/hip_bf16.h>

// ShardAttention R18 = exact R16 (session best, 730.9us measured R13).
// R17's shuffle-packed scores stores regressed (+29us): partial-line P
// stores were already L2-absorbed; shuffle chains added critical-path VALU
// and idled lanes. Reverted.
// Final composition: LDS-staged symmetric scores (136 tiles) + 256^2
// 5-barrier slipped GEMM (counted vmcnt(6), both-sides swizzle, setprio,
// XCD-swizzle) + proj split-K KZ=4 + bf16 partials reduce.

typedef __hip_bfloat16 bf16;
typedef __bf16 bf16x8 __attribute__((ext_vector_type(8)));
typedef float f32x4 __attribute__((ext_vector_type(4)));

#define B_ 2
#define T_ 2048
#define C_ 1024
#define H_ 16
#define D_ 16384
#define E_ 1024
#define KZ_ 4  // proj split-K chunks

__device__ __forceinline__ void load_lds16(const void* g, void* l) {
  __builtin_amdgcn_global_load_lds(
      (const __attribute__((address_space(1))) void*)g,
      (__attribute__((address_space(3))) void*)l, 16, 0, 0);
}

__device__ __forceinline__ unsigned pack2(float a, float b) {
  union { bf16 h[2]; unsigned u; } p;
  p.h[0] = __float2bfloat16(a);
  p.h[1] = __float2bfloat16(b);
  return p.u;
}

// ---------------- transpose + fp32->bf16 cast ----------------
__global__ __launch_bounds__(256) void transpose_cast_kernel(
    const float* __restrict__ in, bf16* __restrict__ out, int rows, int cols) {
  __shared__ float tile[32][33];
  size_t zoff = (size_t)blockIdx.z * rows * cols;
  int c0 = blockIdx.x * 32, r0 = blockIdx.y * 32;
  int tx = threadIdx.x, ty = threadIdx.y;
  for (int i = ty; i < 32; i += 8)
    tile[i][tx] = in[zoff + (size_t)(r0 + i) * cols + c0 + tx];
  __syncthreads();
  for (int i = ty; i < 32; i += 8)
    out[zoff + (size_t)(c0 + i) * rows + r0 + tx] = __float2bfloat16(tile[tx][i]);
}

// ---------------- x -> per-head bf16 [b][h][t][64] ----------------
__global__ __launch_bounds__(256) void xh_cast_kernel(
    const float* __restrict__ x, bf16* __restrict__ xh) {
  int bt = blockIdx.x;
  int b = bt >> 11, t = bt & (T_ - 1);
  float4 v = ((const float4*)(x + (size_t)bt * C_))[threadIdx.x];
  int c = threadIdx.x * 4;
  int h = c >> 6, k = c & 63;
  bf16* o = xh + ((size_t)(b * H_ + h) * T_ + t) * 64 + k;
  o[0] = __float2bfloat16(v.x);
  o[1] = __float2bfloat16(v.y);
  o[2] = __float2bfloat16(v.z);
  o[3] = __float2bfloat16(v.w);
}

// ---------------- reduce KZ_ bf16 partials -> f32 out ----------------
__global__ __launch_bounds__(256) void reduce_kernel(
    const bf16* __restrict__ p, float* __restrict__ out, int n8) {
  int i = blockIdx.x * 256 + threadIdx.x;
  if (i >= n8) return;
  float a[8] = {};
#pragma unroll
  for (int z = 0; z < KZ_; ++z) {
    bf16x8 v = ((const bf16x8*)(p + (size_t)z * n8 * 8))[i];
#pragma unroll
    for (int k = 0; k < 8; ++k) a[k] += (float)v[k];
  }
  float4 lo = make_float4(a[0], a[1], a[2], a[3]);
  float4 hi = make_float4(a[4], a[5], a[6], a[7]);
  ((float4*)out)[2 * i] = lo;
  ((float4*)out)[2 * i + 1] = hi;
}

// ---------------- scores: symmetric tiles, K=64, exp + sums ----------------
__global__ __launch_bounds__(256) void scores_kernel(
    const bf16* __restrict__ xh,  // [Hs][T][64]
    bf16* __restrict__ P,         // [Hs][T][T]
    float* __restrict__ lsum) {   // [Hs][T], pre-zeroed
  int L = blockIdx.x;
  int z = blockIdx.y;
  int ti = 0, rem = L;
  while (rem >= H_ - ti) { rem -= H_ - ti; ++ti; }
  int tj = ti + rem;  // ti <= tj

  const bf16* A = xh + (size_t)z * T_ * 64;
  bf16* Pz = P + (size_t)z * T_ * T_;
  size_t row0 = (size_t)ti * 128, col0 = (size_t)tj * 128;

  __shared__ bf16 lds_a[128 * 64];
  __shared__ bf16 lds_b[128 * 64];
  int t = threadIdx.x;

  const bf16* ga = A + (row0 + (t >> 3)) * 64 + (t & 7) * 8;
  const bf16* gb = A + (col0 + (t >> 3)) * 64 + (t & 7) * 8;
#pragma unroll
  for (int q = 0; q < 4; ++q) {
    load_lds16(ga + q * 32 * 64, lds_a + t * 8 + q * 2048);
    load_lds16(gb + q * 32 * 64, lds_b + t * 8 + q * 2048);
  }
  __syncthreads();

  int lane = t & 63, w = t >> 6;
  int wm = (w & 1) * 64, wn = (w >> 1) * 64;
  int lr = lane & 15, lq = lane >> 4;
  const int a_off = (wm + lr) * 64 + lq * 8;
  const int b_off = (wn + lr) * 64 + lq * 8;

  f32x4 acc[4][4] = {};
#pragma unroll
  for (int kh = 0; kh < 2; ++kh) {
    bf16x8 af[4], bfr[4];
#pragma unroll
    for (int i = 0; i < 4; ++i)
      af[i] = *(const bf16x8*)&lds_a[a_off + kh * 32 + i * 16 * 64];
#pragma unroll
    for (int j = 0; j < 4; ++j)
      bfr[j] = *(const bf16x8*)&lds_b[b_off + kh * 32 + j * 16 * 64];
#pragma unroll
    for (int i = 0; i < 4; ++i)
#pragma unroll
      for (int j = 0; j < 4; ++j)
        acc[i][j] = __builtin_amdgcn_mfma_f32_16x16x32_bf16(af[i], bfr[j],
                                                            acc[i][j], 0, 0, 0);
  }

  float rs[4][4];
  float cs[4];
#pragma unroll
  for (int i2 = 0; i2 < 4; ++i2)
#pragma unroll
    for (int reg = 0; reg < 4; ++reg) rs[i2][reg] = 0.f;
#pragma unroll
  for (int j2 = 0; j2 < 4; ++j2) cs[j2] = 0.f;

#pragma unroll
  for (int i2 = 0; i2 < 4; ++i2) {
    size_t rb = row0 + wm + i2 * 16 + lq * 4;
#pragma unroll
    for (int j2 = 0; j2 < 4; ++j2) {
      size_t c = col0 + wn + j2 * 16 + lr;
      float e[4];
#pragma unroll
      for (int reg = 0; reg < 4; ++reg) {
        e[reg] = __expf(acc[i2][j2][reg] * 0.125f);
        rs[i2][reg] += e[reg];
        cs[j2] += e[reg];
        float nb = __shfl_xor(e[reg], 1);
        if ((lr & 1) == 0)
          *(unsigned*)&Pz[(rb + reg) * T_ + c] = pack2(e[reg], nb);
      }
      uint2 mv;
      mv.x = pack2(e[0], e[1]);
      mv.y = pack2(e[2], e[3]);
      *(uint2*)&Pz[c * T_ + rb] = mv;
    }
  }

#pragma unroll
  for (int i2 = 0; i2 < 4; ++i2)
#pragma unroll
    for (int reg = 0; reg < 4; ++reg) {
#pragma unroll
      for (int off = 1; off < 16; off <<= 1)
        rs[i2][reg] += __shfl_xor(rs[i2][reg], off);
    }
  if (lr == 0) {
#pragma unroll
    for (int i2 = 0; i2 < 4; ++i2) {
      size_t rb = row0 + wm + i2 * 16 + lq * 4;
#pragma unroll
      for (int reg = 0; reg < 4; ++reg)
        atomicAdd(&lsum[(size_t)z * T_ + rb + reg], rs[i2][reg]);
    }
  }
  if (ti != tj) {
#pragma unroll
    for (int j2 = 0; j2 < 4; ++j2) {
      cs[j2] += __shfl_xor(cs[j2], 16);
      cs[j2] += __shfl_xor(cs[j2], 32);
    }
    if (lq == 0) {
#pragma unroll
      for (int j2 = 0; j2 < 4; ++j2) {
        size_t c = col0 + wn + j2 * 16 + lr;
        atomicAdd(&lsum[(size_t)z * T_ + c], cs[j2]);
      }
    }
  }
}

// ---------------- 256^2 bf16 NT GEMM (R8: 5-bar slipped, vmcnt(6)) ----------
template <int IH, int JH>
__device__ __forceinline__ void quad(f32x4 (&acc)[8][4], const bf16x8 (&aR)[8],
                                     const bf16x8 (&bR)[4]) {
#pragma unroll
  for (int i = 0; i < 4; ++i)
#pragma unroll
    for (int jj = 0; jj < 2; ++jj)
#pragma unroll
      for (int kk = 0; kk < 2; ++kk)
        acc[IH * 4 + i][JH * 2 + jj] = __builtin_amdgcn_mfma_f32_16x16x32_bf16(
            aR[i * 2 + kk], bR[jj * 2 + kk], acc[IH * 4 + i][JH * 2 + jj], 0, 0,
            0);
}

#define STAGE_A(bufi, h, tau)                                                 \
  do {                                                                        \
    load_lds16(Ab + offA[(h)*2 + 0] + (size_t)(tau)*64,                       \
               &ldsA[bufi][(((h)*512) + t) * 8]);                             \
    load_lds16(Ab + offA[(h)*2 + 1] + (size_t)(tau)*64,                       \
               &ldsA[bufi][((1024 + (h)*512) + t) * 8]);                      \
  } while (0)

#define STAGE_B(bufi, h, tau)                                                 \
  do {                                                                        \
    load_lds16(Bb + offB[(h)*2 + 0] + (size_t)(tau)*64,                       \
               &ldsB[bufi][(((t >> 8) * 512) + (h)*256 + (t & 255)) * 8]);    \
    load_lds16(                                                               \
        Bb + offB[(h)*2 + 1] + (size_t)(tau)*64,                              \
        &ldsB[bufi][((((t + 512) >> 8) * 512) + (h)*256 + (t & 255)) * 8]);   \
  } while (0)

#define RD_A(dst, d, add)                                                     \
  do {                                                                        \
    dst[0] = *(const bf16x8*)&ldsA[d][aoff[0] + (add)];                       \
    dst[1] = *(const bf16x8*)&ldsA[d][aoff[1] + (add)];                       \
    dst[2] = *(const bf16x8*)&ldsA[d][aoff[2] + (add)];                       \
    dst[3] = *(const bf16x8*)&ldsA[d][aoff[3] + (add)];                       \
    dst[4] = *(const bf16x8*)&ldsA[d][aoff[4] + (add)];                       \
    dst[5] = *(const bf16x8*)&ldsA[d][aoff[5] + (add)];                       \
    dst[6] = *(const bf16x8*)&ldsA[d][aoff[6] + (add)];                       \
    dst[7] = *(const bf16x8*)&ldsA[d][aoff[7] + (add)];                       \
  } while (0)

#define RD_B(dst, d, add)                                                     \
  do {                                                                        \
    dst[0] = *(const bf16x8*)&ldsB[d][boff[0] + (add)];                       \
    dst[1] = *(const bf16x8*)&ldsB[d][boff[1] + (add)];                       \
    dst[2] = *(const bf16x8*)&ldsB[d][boff[2] + (add)];                       \
    dst[3] = *(const bf16x8*)&ldsB[d][boff[3] + (add)];                       \
  } while (0)

// MODE 1: pack-store bf16   MODE 3: pack-store bf16(v / lsum[bz*lzs + r])
template <int MODE, int SWZ>
__global__ __launch_bounds__(512, 2) void gemm256_kernel(
    const bf16* __restrict__ A, long long a_zstride, int lda,
    const bf16* __restrict__ BT, long long b_zstride, int ldb,
    void* __restrict__ Cout, int ldc, long long c_zflat,
    const float* __restrict__ lsum, int lzs, int K) {
  __shared__ __align__(16) bf16 ldsA[2][256 * 64];
  __shared__ __align__(16) bf16 ldsB[2][256 * 64];
  const int t = threadIdx.x;

  int bx = blockIdx.x, by = blockIdx.y, bz = blockIdx.z;
  if (SWZ) {
    int gx = gridDim.x, gy = gridDim.y, gz = gridDim.z;
    int S = gy * gz, nb = gx * S;
    if (((S & 7) == 0) && ((nb & 7) == 0)) {
      int L = bx + gx * (by + gy * bz);
      int xcd = L & 7, m = L >> 3, spx = S >> 3;
      int col = m % gx, sl = m / gx;
      int strip = xcd * spx + sl;
      bx = col; by = strip % gy; bz = strip / gy;
    }
  }

  const bf16* Ab = A + (size_t)bz * a_zstride;
  const bf16* Bb = BT + (size_t)bz * b_zstride;
  const size_t row0 = (size_t)by * 256;
  const size_t col0 = (size_t)bx * 256;
  const int NT = K >> 6;

  // staging source element-offsets (swizzle involution pre-applied to SOURCE)
  int offA[4], offB[4];
#pragma unroll
  for (int h = 0; h < 2; ++h)
#pragma unroll
    for (int l = 0; l < 2; ++l) {
      int s = h * 512 + l * 1024 + t;
      int src = s ^ ((s >> 3) & 7);
      offA[h * 2 + l] =
          (int)((row0 + (size_t)(src >> 3)) * (size_t)lda) + (src & 7) * 8;
      int u = t + l * 512;
      int sb = (u >> 8) * 512 + h * 256 + (u & 255);
      int srcb = sb ^ ((sb >> 3) & 7);
      offB[h * 2 + l] =
          (int)((col0 + (size_t)(srcb >> 3)) * (size_t)ldb) + (srcb & 7) * 8;
    }

  // fragment read offsets (elements), swizzled: phys = logical ^ ((row&7)<<3)
  const int lane = t & 63, w = t >> 6;
  const int wr = w >> 2, wc = w & 3;
  const int lr = lane & 15, lq = lane >> 4;
  const int axor = (lr & 7) << 3;
  int aoff[8], boff[4];
#pragma unroll
  for (int i = 0; i < 4; ++i)
#pragma unroll
    for (int kk = 0; kk < 2; ++kk)
      aoff[i * 2 + kk] =
          (((wr * 128 + i * 16 + lr) * 64) + kk * 32 + lq * 8) ^ axor;
#pragma unroll
  for (int j = 0; j < 2; ++j)
#pragma unroll
    for (int kk = 0; kk < 2; ++kk)
      boff[j * 2 + kk] =
          (((wc * 64 + j * 16 + lr) * 64) + kk * 32 + lq * 8) ^ axor;

  f32x4 acc[8][4] = {};
  bf16x8 aR[8], bR0[4], bR1[4];

  // prologue: stream A0(0),B0(0),B1(0),A1(0),A0(1),B0(1),B1(1); drain to 3 halves
  {
    const int t1 = (NT > 1) ? 1 : 0;
    STAGE_A(0, 0, 0);
    STAGE_B(0, 0, 0);
    STAGE_B(0, 1, 0);
    STAGE_A(0, 1, 0);
    STAGE_A(1, 0, t1);
    STAGE_B(1, 0, t1);
    STAGE_B(1, 1, t1);
    asm volatile("s_waitcnt vmcnt(6)" ::: "memory");
    __builtin_amdgcn_s_barrier();
  }

  for (int tt = 0; tt < NT; ++tt) {
    const int d = tt & 1, dn = d ^ 1;
    const int tp1 = (tt + 1 < NT) ? (tt + 1) : (NT - 1);
    const int tp2 = (tt + 2 < NT) ? (tt + 2) : (NT - 1);
    // ---- ph1: reads{jh0,ih0}; bar; q(0,0); stage A1(t+1)->dn
    RD_B(bR0, d, 0);
    RD_A(aR, d, 0);
    __builtin_amdgcn_s_barrier();
    __builtin_amdgcn_s_setprio(1);
    quad<0, 0>(acc, aR, bR0);
    __builtin_amdgcn_s_setprio(0);
    STAGE_A(dn, 1, tp1);
    // ---- ph2: reads{jh1}; bar; q(0,1); stage A0(t+2)->d
    RD_B(bR1, d, 2048);
    __builtin_amdgcn_s_barrier();
    __builtin_amdgcn_s_setprio(1);
    quad<0, 1>(acc, aR, bR1);
    __builtin_amdgcn_s_setprio(0);
    STAGE_A(d, 0, tp2);
    // ---- ph3: reads{ih1}; bar; q(1,1); stage B0(t+2)->d
    RD_A(aR, d, 4096);
    __builtin_amdgcn_s_barrier();
    __builtin_amdgcn_s_setprio(1);
    quad<1, 1>(acc, aR, bR1);
    __builtin_amdgcn_s_setprio(0);
    STAGE_B(d, 0, tp2);
    // ---- ph4: bar; q(1,0); stage B1(t+2)->d; counted vmcnt; tile-bar
    __builtin_amdgcn_s_barrier();
    __builtin_amdgcn_s_setprio(1);
    quad<1, 0>(acc, aR, bR0);
    __builtin_amdgcn_s_setprio(0);
    STAGE_B(d, 1, tp2);
    asm volatile("s_waitcnt vmcnt(6)" ::: "memory");
    __builtin_amdgcn_s_barrier();
  }
  // drain outstanding gloads before workgroup retire (LDS reuse safety)
  asm volatile("s_waitcnt vmcnt(0)" ::: "memory");

  // epilogue: C/D layout col=lane&15, row=(lane>>4)*4+reg; column-pair packing
  size_t cbase = (size_t)bz * c_zflat + col0 + wc * 64;
#pragma unroll
  for (int i = 0; i < 8; ++i) {
    size_t r = row0 + wr * 128 + i * 16 + lq * 4;
    float4 inv4 = make_float4(1.f, 1.f, 1.f, 1.f);
    if (MODE == 3) {
      float4 lv = *(const float4*)&lsum[(size_t)bz * lzs + r];
      inv4 = make_float4(1.f / lv.x, 1.f / lv.y, 1.f / lv.z, 1.f / lv.w);
    }
#pragma unroll
    for (int j = 0; j < 4; ++j) {
      size_t c = cbase + j * 16 + lr;
#pragma unroll
      for (int reg = 0; reg < 4; ++reg) {
        float v = acc[i][j][reg];
        if (MODE == 3) {
          float iv = reg == 0 ? inv4.x : reg == 1 ? inv4.y : reg == 2 ? inv4.z
                                                                      : inv4.w;
          v *= iv;
        }
        float nb = __shfl_xor(v, 1);
        if ((lr & 1) == 0) {
          size_t idx = (r + reg) * (size_t)ldc + c;
          *(unsigned*)&((bf16*)Cout)[idx] = pack2(v, nb);
        }
      }
    }
  }
}

extern "C" void kernel_launch(void* const* d_in, const int* in_sizes, int n_in,
                              void* d_out, int out_size, void* d_ws,
                              size_t ws_size, hipStream_t stream) {
  const float* x = (const float*)d_in[0];    // [B, T, C] fp32
  const float* wgt = (const float*)d_in[1];  // [D, E] fp32
  float* out = (float*)d_out;                // [B, T, E] fp32

  // ws layout
  bf16* xbT = (bf16*)d_ws;                        // [B][C][T]    8 MB
  bf16* wbT = xbT + (size_t)B_ * C_ * T_;         // [E][D]      32 MB
  bf16* xh = wbT + (size_t)E_ * D_;               // [B][H][T][64] 8 MB
  bf16* Obuf = xh + (size_t)B_ * H_ * T_ * 64;    // [B*T][D]   128 MB
  float* lsum = (float*)(Obuf + (size_t)B_ * T_ * D_);  // [16][T] 128 KB
  bf16* P = (bf16*)(lsum + (size_t)16 * T_);      // [Hs][T][T] slab 128 MB
  bf16* partials = P;                             // reuse slab (34 MB, KZ=4)

  transpose_cast_kernel<<<dim3(C_ / 32, T_ / 32, B_), dim3(32, 8), 0, stream>>>(
      x, xbT, T_, C_);
  transpose_cast_kernel<<<dim3(E_ / 32, D_ / 32, 1), dim3(32, 8), 0, stream>>>(
      wgt, wbT, D_, E_);
  xh_cast_kernel<<<B_ * T_, 256, 0, stream>>>(x, xh);

  size_t fixed_bytes = ((size_t)B_ * C_ * T_ + (size_t)E_ * D_ +
                        (size_t)B_ * H_ * T_ * 64 + (size_t)B_ * T_ * D_) * 2 +
                       (size_t)16 * T_ * 4;
  int Hs = 16;
  while (Hs > 1 && fixed_bytes + (size_t)Hs * T_ * T_ * 2 > ws_size) Hs >>= 1;

  for (int b = 0; b < B_; ++b) {
    for (int h0 = 0; h0 < H_; h0 += Hs) {
      const bf16* xhb = xh + (size_t)(b * H_ + h0) * T_ * 64;
      hipMemsetAsync(lsum, 0, (size_t)Hs * T_ * sizeof(float), stream);
      scores_kernel<<<dim3(136, Hs), 256, 0, stream>>>(xhb, P, lsum);
      // O = (P @ xbT^T) / l
      gemm256_kernel<3, 1><<<dim3(C_ / 256, T_ / 256, Hs), 512, 0, stream>>>(
          P, (long long)T_ * T_, T_, xbT + (size_t)b * C_ * T_, 0LL, T_,
          (void*)(Obuf + (size_t)b * T_ * D_ + (size_t)h0 * C_), D_,
          (long long)C_, lsum, T_, T_);
    }
  }
  // proj: partials[z] = O[:, z*4096:(z+1)*4096] @ W[z*4096:(z+1)*4096, :]
  gemm256_kernel<1, 1><<<dim3(E_ / 256, (B_ * T_) / 256, KZ_), 512, 0,
                         stream>>>(Obuf, (long long)(D_ / KZ_), D_, wbT,
                                   (long long)(D_ / KZ_), D_, (void*)partials,
                                   E_, (long long)B_ * T_ * E_, nullptr, 0,
                                   D_ / KZ_);
  reduce_kernel<<<(B_ * T_ * E_ / 8 + 255) / 256, 256, 0, stream>>>(
      partials, out, B_ * T_ * E_ / 8);
}